// Round 1
// baseline (688.809 us; speedup 1.0000x reference)
//
#include <hip/hip_runtime.h>
#include <hip/hip_bf16.h>

typedef short bf16x8 __attribute__((ext_vector_type(8)));
typedef float f32x4 __attribute__((ext_vector_type(4)));
typedef unsigned short ushort_t;
typedef unsigned int uint_t;

#define CIN   256
#define COUT  256
#define HWDIM 56
#define IMG   (HWDIM * HWDIM)   // 3136
#define K_TOT (CIN * 9)         // 2304
#define NIMG  32
#define NPIX  (NIMG * IMG)      // 100352
#define BM    128
#define BN    128
#define BK    32

__device__ __forceinline__ ushort_t f2bf(float f) {
    union { float f; uint_t u; } v; v.f = f;
    uint_t u = v.u;
    uint_t r = u + 0x7FFFu + ((u >> 16) & 1u);   // RNE
    return (ushort_t)(r >> 16);
}

// One block per output filter o. Computes delta/alpha, writes ternary SIGNS
// (+1/-1/0 as exact bf16) to wt[o][k] and alpha (fp32) to alpha_out[o].
__global__ __launch_bounds__(256) void ternarize_kernel(
        const float* __restrict__ w,
        ushort_t* __restrict__ wt,
        float* __restrict__ alpha_out) {
    const int o = blockIdx.x;
    const int t = threadIdx.x;
    const int lane = t & 63;
    const int wv = t >> 6;
    const float* base = w + (size_t)o * K_TOT;

    float v[9];
#pragma unroll
    for (int i = 0; i < 9; ++i) v[i] = base[t + 256 * i];

    __shared__ float sred[8];

    // phase 1: sum |w|
    float s = 0.f;
#pragma unroll
    for (int i = 0; i < 9; ++i) s += fabsf(v[i]);
#pragma unroll
    for (int off = 32; off > 0; off >>= 1) s += __shfl_down(s, off);
    if (lane == 0) sred[wv] = s;
    __syncthreads();
    if (t == 0) sred[0] = sred[0] + sred[1] + sred[2] + sred[3];
    __syncthreads();
    const float delta = (0.7f / (float)K_TOT) * sred[0];
    __syncthreads();  // everyone has read sred[0] before phase 2 overwrites

    // phase 2: masked sum + count
    float asum = 0.f, cnt = 0.f;
#pragma unroll
    for (int i = 0; i < 9; ++i) {
        float a = fabsf(v[i]);
        if (a > delta) { asum += a; cnt += 1.f; }
    }
#pragma unroll
    for (int off = 32; off > 0; off >>= 1) {
        asum += __shfl_down(asum, off);
        cnt  += __shfl_down(cnt, off);
    }
    if (lane == 0) { sred[wv] = asum; sred[4 + wv] = cnt; }
    __syncthreads();
    if (t == 0) {
        float at = sred[0] + sred[1] + sred[2] + sred[3];
        float ct = sred[4] + sred[5] + sred[6] + sred[7];
        alpha_out[o] = at / ct;
    }

    // write ternary signs as bf16 bits: +1 -> 0x3F80, -1 -> 0xBF80, 0 -> 0
#pragma unroll
    for (int i = 0; i < 9; ++i) {
        int idx = t + 256 * i;
        float x = v[i];
        ushort_t bits = 0;
        if (x > delta)       bits = 0x3F80u;
        else if (x < -delta) bits = 0xBF80u;
        wt[(size_t)o * K_TOT + idx] = bits;
    }
}

// Implicit-GEMM conv: C[o][p] = sum_k W[o][k] * X[k][p],
// k = c*9 + kh*3 + kw,  p = n*3136 + h*56 + w,  X gathered with zero-padding.
// 128x128 tile per block, BK=32, 4 waves each computing 4x4 of 16x16x32 MFMA.
__global__ __launch_bounds__(256) void tern_conv_kernel(
        const float* __restrict__ x,
        const ushort_t* __restrict__ wt,
        const float* __restrict__ alpha,
        const float* __restrict__ bias,
        float* __restrict__ out) {
    __shared__ __align__(16) ushort_t As[BM * BK];  // [o][kk], stride 32
    __shared__ __align__(16) ushort_t Xs[BN * BK];  // [p][kk], stride 32

    const int tid = threadIdx.x;
    const int bid = blockIdx.x;
    const int tile_m = bid & 1;     // 2 M-tiles
    const int tile_n = bid >> 1;    // 784 N-tiles
    const int o0 = tile_m * BM;
    const int p0 = tile_n * BN;

    // staging assignment: srow = output-row (A) / pixel-col (X); sseg = 16-wide k segment
    const int srow = tid & 127;
    const int sseg = tid >> 7;

    // decode this thread's pixel once (same for every K-step)
    const int p = p0 + srow;
    const int n_img = p / IMG;
    const int hw_ = p - n_img * IMG;
    const int h = hw_ / HWDIM;
    const int w_ = hw_ - h * HWDIM;
    const float* xbase = x + (size_t)n_img * CIN * IMG;

    const int lane = tid & 63;
    const int wv = tid >> 6;
    const int wave_m = (wv >> 1) * 64;
    const int wave_n = (wv & 1) * 64;
    const int qd = lane >> 4;
    const int ln = lane & 15;

    f32x4 acc[4][4];
#pragma unroll
    for (int i = 0; i < 4; ++i)
#pragma unroll
        for (int j = 0; j < 4; ++j)
            acc[i][j] = (f32x4){0.f, 0.f, 0.f, 0.f};

    for (int k0 = 0; k0 < K_TOT; k0 += BK) {
        // ---- global fetch (before barrier, overlaps previous compute) ----
        const ushort_t* wsrc = wt + (size_t)(o0 + srow) * K_TOT + k0 + sseg * 16;
        const uint4 a0 = *(const uint4*)(wsrc);
        const uint4 a1 = *(const uint4*)(wsrc + 8);

        int k = k0 + sseg * 16;
        int c = k / 9;
        int r = k - c * 9;
        int kh = r / 3;
        int kw = r - kh * 3;
        ushort_t xv[16];
#pragma unroll
        for (int j = 0; j < 16; ++j) {
            const int h2 = h + kh - 1;
            const int w2 = w_ + kw - 1;
            float val = 0.f;
            if ((unsigned)h2 < (unsigned)HWDIM && (unsigned)w2 < (unsigned)HWDIM)
                val = xbase[c * IMG + h2 * HWDIM + w2];
            xv[j] = f2bf(val);
            if (++kw == 3) { kw = 0; if (++kh == 3) { kh = 0; ++c; } }
        }

        __syncthreads();  // previous iteration's fragment reads complete

        *(uint4*)&As[srow * BK + sseg * 16]     = a0;
        *(uint4*)&As[srow * BK + sseg * 16 + 8] = a1;

        uint_t u[8];
#pragma unroll
        for (int q = 0; q < 8; ++q)
            u[q] = (uint_t)xv[2 * q] | ((uint_t)xv[2 * q + 1] << 16);
        *(uint4*)&Xs[srow * BK + sseg * 16]     = (uint4){u[0], u[1], u[2], u[3]};
        *(uint4*)&Xs[srow * BK + sseg * 16 + 8] = (uint4){u[4], u[5], u[6], u[7]};

        __syncthreads();

        // ---- fragments + MFMA ----
        bf16x8 af[4], bfr[4];
#pragma unroll
        for (int i = 0; i < 4; ++i)
            af[i] = *(const bf16x8*)&As[(wave_m + i * 16 + ln) * BK + qd * 8];
#pragma unroll
        for (int i = 0; i < 4; ++i)
            bfr[i] = *(const bf16x8*)&Xs[(wave_n + i * 16 + ln) * BK + qd * 8];

#pragma unroll
        for (int im = 0; im < 4; ++im)
#pragma unroll
            for (int in2 = 0; in2 < 4; ++in2)
                acc[im][in2] = __builtin_amdgcn_mfma_f32_16x16x32_bf16(
                    af[im], bfr[in2], acc[im][in2], 0, 0, 0);
    }

    // ---- epilogue: out[n][o][h][w] = alpha[o]*acc + bias[o] ----
#pragma unroll
    for (int in2 = 0; in2 < 4; ++in2) {
        const int pc = p0 + wave_n + in2 * 16 + ln;
        const int ni = pc / IMG;
        const int hwc = pc - ni * IMG;
        const size_t obase = (size_t)ni * COUT * IMG + hwc;
#pragma unroll
        for (int im = 0; im < 4; ++im) {
            const int orow = o0 + wave_m + im * 16 + qd * 4;
#pragma unroll
            for (int rr = 0; rr < 4; ++rr) {
                const int o = orow + rr;
                out[obase + (size_t)o * IMG] = alpha[o] * acc[im][in2][rr] + bias[o];
            }
        }
    }
}

extern "C" void kernel_launch(void* const* d_in, const int* in_sizes, int n_in,
                              void* d_out, int out_size, void* d_ws, size_t ws_size,
                              hipStream_t stream) {
    const float* x      = (const float*)d_in[0];
    const float* weight = (const float*)d_in[1];
    const float* bias   = (const float*)d_in[2];
    float* out = (float*)d_out;

    // workspace layout: [0, 256*2304*2) ternary-sign bf16 table; then 256 fp32 alphas
    ushort_t* wt    = (ushort_t*)d_ws;
    float*    alpha = (float*)((char*)d_ws + (size_t)COUT * K_TOT * sizeof(ushort_t));

    ternarize_kernel<<<COUT, 256, 0, stream>>>(weight, wt, alpha);

    const int n_blocks = (COUT / BM) * (NPIX / BN);  // 2 * 784 = 1568
    tern_conv_kernel<<<n_blocks, 256, 0, stream>>>(x, wt, alpha, bias, out);
}

// Round 2
// 375.714 us; speedup vs baseline: 1.8333x; 1.8333x over previous
//
#include <hip/hip_runtime.h>
#include <hip/hip_bf16.h>
#include <stdint.h>

typedef short bf16x8 __attribute__((ext_vector_type(8)));
typedef float f32x4 __attribute__((ext_vector_type(4)));
typedef unsigned short ushort_t;
typedef unsigned int uint_t;

#define CIN   256
#define COUT  256
#define HWDIM 56
#define IMG   (HWDIM * HWDIM)   // 3136
#define K_TOT (CIN * 9)         // 2304
#define NIMG  32
#define NPIX  (NIMG * IMG)      // 100352
#define BM    128
#define BN    128
#define BK    32                 // channels per K-step

// "evil way" addrspace casts (CK-style) for global_load_lds
#define AS1CAST(p) ((const __attribute__((address_space(1))) unsigned int*)(uintptr_t)(p))
#define AS3CAST(p) ((__attribute__((address_space(3))) unsigned int*)(uintptr_t)(p))

__device__ __forceinline__ ushort_t f2bf(float f) {
    union { float f; uint_t u; } v; v.f = f;
    uint_t u = v.u;
    uint_t r = u + 0x7FFFu + ((u >> 16) & 1u);   // RNE
    return (ushort_t)(r >> 16);
}

// ---------------------------------------------------------------------------
// Ternarize: per-filter delta/alpha; write SIGNS as exact bf16 into layout
// wt2[o][kpos][c] (kpos = kh*3+kw) so conv A-tiles are channel-contiguous.
// Block 0 also zeroes the xt halo pad row (row NPIX).
// ---------------------------------------------------------------------------
__global__ __launch_bounds__(256) void ternarize_kernel(
        const float* __restrict__ w,
        ushort_t* __restrict__ wt2,
        float* __restrict__ alpha_out,
        ushort_t* __restrict__ xt_pad_row) {
    const int o = blockIdx.x;
    const int t = threadIdx.x;
    const int lane = t & 63;
    const int wv = t >> 6;
    const float* base = w + (size_t)o * K_TOT;

    if (o == 0 && t < 32) ((uint4*)xt_pad_row)[t] = (uint4){0u, 0u, 0u, 0u};

    float v[9];
#pragma unroll
    for (int i = 0; i < 9; ++i) v[i] = base[t + 256 * i];

    __shared__ float sred[8];

    float s = 0.f;
#pragma unroll
    for (int i = 0; i < 9; ++i) s += fabsf(v[i]);
#pragma unroll
    for (int off = 32; off > 0; off >>= 1) s += __shfl_down(s, off);
    if (lane == 0) sred[wv] = s;
    __syncthreads();
    if (t == 0) sred[0] = sred[0] + sred[1] + sred[2] + sred[3];
    __syncthreads();
    const float delta = (0.7f / (float)K_TOT) * sred[0];
    __syncthreads();

    float asum = 0.f, cnt = 0.f;
#pragma unroll
    for (int i = 0; i < 9; ++i) {
        float a = fabsf(v[i]);
        if (a > delta) { asum += a; cnt += 1.f; }
    }
#pragma unroll
    for (int off = 32; off > 0; off >>= 1) {
        asum += __shfl_down(asum, off);
        cnt  += __shfl_down(cnt, off);
    }
    if (lane == 0) { sred[wv] = asum; sred[4 + wv] = cnt; }
    __syncthreads();
    if (t == 0) {
        float at = sred[0] + sred[1] + sred[2] + sred[3];
        float ct = sred[4] + sred[5] + sred[6] + sred[7];
        alpha_out[o] = at / ct;
    }

#pragma unroll
    for (int i = 0; i < 9; ++i) {
        int idx = t + 256 * i;           // flat k = c*9 + r
        int c = idx / 9;
        int r = idx - c * 9;
        float x = v[i];
        ushort_t bits = 0;
        if (x > delta)       bits = 0x3F80u;
        else if (x < -delta) bits = 0xBF80u;
        wt2[(size_t)o * K_TOT + r * 256 + c] = bits;
    }
}

// ---------------------------------------------------------------------------
// Transpose + convert: x NCHW fp32 -> xt [pixel][channel] bf16 (NHWC).
// 32x32 tiles through LDS (pad 33 -> conflict-free).
// ---------------------------------------------------------------------------
__global__ __launch_bounds__(256) void transpose_kernel(
        const float* __restrict__ x, ushort_t* __restrict__ xt) {
    __shared__ float L[32][33];
    const int hw0 = blockIdx.x * 32;
    const int c0  = blockIdx.y * 32;
    const int n   = blockIdx.z;
    const int t = threadIdx.x;
    const int tx = t & 31, ty = t >> 5;  // 32 x 8

    const float* xb = x + ((size_t)n * CIN + c0) * IMG + hw0;
#pragma unroll
    for (int j = 0; j < 4; ++j)
        L[ty + j * 8][tx] = xb[(size_t)(ty + j * 8) * IMG + tx];
    __syncthreads();

    const int cl  = (t & 15) * 2;   // channel pair
    const int hwy = t >> 4;         // 16 hw rows per pass
    ushort_t* ob = xt + ((size_t)(n * IMG + hw0)) * CIN + c0;
#pragma unroll
    for (int j = 0; j < 2; ++j) {
        int hwl = hwy + j * 16;
        uint_t pk = (uint_t)f2bf(L[cl][hwl]) | ((uint_t)f2bf(L[cl + 1][hwl]) << 16);
        *(uint_t*)&ob[(size_t)hwl * CIN + cl] = pk;
    }
}

// ---------------------------------------------------------------------------
// Implicit-GEMM conv, m97 structure: 128x128 tile, BK=32 channels,
// loop kpos(9) x c0(8). A and B staged via global_load_lds width=16 with
// XOR-swizzled 16B segments (2-way bank aliasing on ds_read_b128 = free).
// Halo pixels redirect to the zeroed pad row (row NPIX of xt).
// ---------------------------------------------------------------------------
__global__ __launch_bounds__(256) void tern_conv_kernel(
        const ushort_t* __restrict__ xt,    // [(NPIX+1)][256]
        const ushort_t* __restrict__ wt2,   // [256 o][9][256 c]
        const float* __restrict__ alpha,
        const float* __restrict__ bias,
        float* __restrict__ out) {
    __shared__ __align__(16) ushort_t As[BM * BK];
    __shared__ __align__(16) ushort_t Xs[BN * BK];

    const int tid = threadIdx.x;
    const int wv = tid >> 6;
    const int l = tid & 63;
    const int bid = blockIdx.x;
    const int o0 = (bid & 1) * BM;
    const int p0 = (bid >> 1) * BN;

    // staging geometry: each wave stages 2 chunks of 16 rows (rows wv*32..+31)
    const int srow = l >> 2;                     // row within 16-row chunk
    const int gseg = (l & 3) ^ ((l >> 3) & 3);   // swizzled source 16B segment

    // A source pointers (row-major, 9*256 per o-row), without kpos/c offsets
    const ushort_t* pa0 = wt2 + (size_t)(o0 + wv * 32 + srow) * K_TOT + gseg * 8;
    const ushort_t* pa1 = pa0 + (size_t)16 * K_TOT;

    // decode the two B pixels this thread stages
    int pn[2], ph[2], pw_[2];
#pragma unroll
    for (int j = 0; j < 2; ++j) {
        int p = p0 + wv * 32 + j * 16 + srow;
        int n_img = p / IMG;
        int hw_ = p - n_img * IMG;
        ph[j] = hw_ / HWDIM;
        pw_[j] = hw_ - ph[j] * HWDIM;
        pn[j] = n_img * IMG;
    }

    // fragment-read geometry (LDS addresses are loop-invariant)
    const int qd = l >> 4, ln = l & 15;
    const int wm = (wv >> 1) * 64, wn = (wv & 1) * 64;
    const int fsg = qd ^ ((ln >> 1) & 3);        // de-swizzle segment

    f32x4 acc[4][4];
#pragma unroll
    for (int i = 0; i < 4; ++i)
#pragma unroll
        for (int j = 0; j < 4; ++j)
            acc[i][j] = (f32x4){0.f, 0.f, 0.f, 0.f};

#pragma unroll 1
    for (int kpos = 0; kpos < 9; ++kpos) {
        const int dh = kpos / 3 - 1;
        const int dw = kpos - (dh + 1) * 3 - 1;

        const ushort_t* a0 = pa0 + kpos * 256;
        const ushort_t* a1 = pa1 + kpos * 256;

        const ushort_t* b[2];
#pragma unroll
        for (int j = 0; j < 2; ++j) {
            int h2 = ph[j] + dh, w2 = pw_[j] + dw;
            int rowoff = ((unsigned)h2 < (unsigned)HWDIM && (unsigned)w2 < (unsigned)HWDIM)
                             ? (pn[j] + h2 * HWDIM + w2) : NPIX;
            b[j] = xt + (size_t)rowoff * CIN + gseg * 8;
        }

        for (int c0 = 0; c0 < CIN; c0 += BK) {
            __syncthreads();   // previous step's fragment reads complete
            __builtin_amdgcn_global_load_lds(AS1CAST(a0 + c0), AS3CAST(&As[(wv * 32) * BK]),      16, 0, 0);
            __builtin_amdgcn_global_load_lds(AS1CAST(a1 + c0), AS3CAST(&As[(wv * 32 + 16) * BK]), 16, 0, 0);
            __builtin_amdgcn_global_load_lds(AS1CAST(b[0] + c0), AS3CAST(&Xs[(wv * 32) * BK]),      16, 0, 0);
            __builtin_amdgcn_global_load_lds(AS1CAST(b[1] + c0), AS3CAST(&Xs[(wv * 32 + 16) * BK]), 16, 0, 0);
            __syncthreads();   // staging complete (vmcnt(0) before barrier)

            bf16x8 af[4], bfr[4];
#pragma unroll
            for (int i = 0; i < 4; ++i)
                af[i] = *(const bf16x8*)&As[(wm + i * 16 + ln) * BK + fsg * 8];
#pragma unroll
            for (int i = 0; i < 4; ++i)
                bfr[i] = *(const bf16x8*)&Xs[(wn + i * 16 + ln) * BK + fsg * 8];

#pragma unroll
            for (int im = 0; im < 4; ++im)
#pragma unroll
                for (int in2 = 0; in2 < 4; ++in2)
                    acc[im][in2] = __builtin_amdgcn_mfma_f32_16x16x32_bf16(
                        af[im], bfr[in2], acc[im][in2], 0, 0, 0);
        }
    }

    // epilogue: out[n][o][h][w] = alpha[o]*acc + bias[o]
#pragma unroll
    for (int in2 = 0; in2 < 4; ++in2) {
        const int pc = p0 + wn + in2 * 16 + ln;
        const int ni = pc / IMG;
        const int hwc = pc - ni * IMG;
        const size_t obase = (size_t)ni * COUT * IMG + hwc;
#pragma unroll
        for (int im = 0; im < 4; ++im) {
            const int orow = o0 + wm + im * 16 + qd * 4;
#pragma unroll
            for (int rr = 0; rr < 4; ++rr) {
                const int o = orow + rr;
                out[obase + (size_t)o * IMG] = alpha[o] * acc[im][in2][rr] + bias[o];
            }
        }
    }
}

extern "C" void kernel_launch(void* const* d_in, const int* in_sizes, int n_in,
                              void* d_out, int out_size, void* d_ws, size_t ws_size,
                              hipStream_t stream) {
    const float* x      = (const float*)d_in[0];
    const float* weight = (const float*)d_in[1];
    const float* bias   = (const float*)d_in[2];
    float* out = (float*)d_out;

    // workspace layout:
    //   xt : (NPIX+1) * 256 bf16  = 51,380,736 B   (last row = zero halo row)
    //   wt2: 256 * 2304 bf16      =  1,179,648 B
    //   alpha: 256 fp32           =      1,024 B
    ushort_t* xt    = (ushort_t*)d_ws;
    ushort_t* wt2   = (ushort_t*)((char*)d_ws + (size_t)(NPIX + 1) * CIN * sizeof(ushort_t));
    float*    alphav = (float*)((char*)wt2 + (size_t)COUT * K_TOT * sizeof(ushort_t));

    ternarize_kernel<<<COUT, 256, 0, stream>>>(weight, wt2, alphav,
                                               xt + (size_t)NPIX * CIN);

    dim3 tg(IMG / 32, CIN / 32, NIMG);  // 98 x 8 x 32
    transpose_kernel<<<tg, 256, 0, stream>>>(x, xt);

    const int n_blocks = (COUT / BM) * (NPIX / BN);  // 1568
    tern_conv_kernel<<<n_blocks, 256, 0, stream>>>(xt, wt2, alphav, bias, out);
}

// Round 3
// 314.754 us; speedup vs baseline: 2.1884x; 1.1937x over previous
//
#include <hip/hip_runtime.h>
#include <hip/hip_bf16.h>
#include <stdint.h>

typedef short bf16x8 __attribute__((ext_vector_type(8)));
typedef float f32x4 __attribute__((ext_vector_type(4)));
typedef unsigned short ushort_t;
typedef unsigned int uint_t;

#define CIN   256
#define COUT  256
#define HWDIM 56
#define IMG   (HWDIM * HWDIM)   // 3136
#define K_TOT (CIN * 9)         // 2304
#define NIMG  32
#define NPIX  (NIMG * IMG)      // 100352
#define BM    128
#define BN    128
#define BK    64                 // channels per staging step (2 MFMA chunks)

#define AS1CAST(p) ((const __attribute__((address_space(1))) unsigned int*)(uintptr_t)(p))
#define AS3CAST(p) ((__attribute__((address_space(3))) unsigned int*)(uintptr_t)(p))

__device__ __forceinline__ ushort_t f2bf(float f) {
    union { float f; uint_t u; } v; v.f = f;
    uint_t u = v.u;
    uint_t r = u + 0x7FFFu + ((u >> 16) & 1u);   // RNE
    return (ushort_t)(r >> 16);
}

// ---------------------------------------------------------------------------
// Ternarize: per-filter delta/alpha; signs as exact bf16 into wt2[o][kpos][c].
// Block 0 also zeroes the xt halo pad row (row NPIX).
// ---------------------------------------------------------------------------
__global__ __launch_bounds__(256) void ternarize_kernel(
        const float* __restrict__ w,
        ushort_t* __restrict__ wt2,
        float* __restrict__ alpha_out,
        ushort_t* __restrict__ xt_pad_row) {
    const int o = blockIdx.x;
    const int t = threadIdx.x;
    const int lane = t & 63;
    const int wv = t >> 6;
    const float* base = w + (size_t)o * K_TOT;

    if (o == 0 && t < 32) ((uint4*)xt_pad_row)[t] = (uint4){0u, 0u, 0u, 0u};

    float v[9];
#pragma unroll
    for (int i = 0; i < 9; ++i) v[i] = base[t + 256 * i];

    __shared__ float sred[8];

    float s = 0.f;
#pragma unroll
    for (int i = 0; i < 9; ++i) s += fabsf(v[i]);
#pragma unroll
    for (int off = 32; off > 0; off >>= 1) s += __shfl_down(s, off);
    if (lane == 0) sred[wv] = s;
    __syncthreads();
    if (t == 0) sred[0] = sred[0] + sred[1] + sred[2] + sred[3];
    __syncthreads();
    const float delta = (0.7f / (float)K_TOT) * sred[0];
    __syncthreads();

    float asum = 0.f, cnt = 0.f;
#pragma unroll
    for (int i = 0; i < 9; ++i) {
        float a = fabsf(v[i]);
        if (a > delta) { asum += a; cnt += 1.f; }
    }
#pragma unroll
    for (int off = 32; off > 0; off >>= 1) {
        asum += __shfl_down(asum, off);
        cnt  += __shfl_down(cnt, off);
    }
    if (lane == 0) { sred[wv] = asum; sred[4 + wv] = cnt; }
    __syncthreads();
    if (t == 0) {
        float at = sred[0] + sred[1] + sred[2] + sred[3];
        float ct = sred[4] + sred[5] + sred[6] + sred[7];
        alpha_out[o] = at / ct;
    }

#pragma unroll
    for (int i = 0; i < 9; ++i) {
        int idx = t + 256 * i;           // flat k = c*9 + r
        int c = idx / 9;
        int r = idx - c * 9;
        float x = v[i];
        ushort_t bits = 0;
        if (x > delta)       bits = 0x3F80u;
        else if (x < -delta) bits = 0xBF80u;
        wt2[(size_t)o * K_TOT + r * 256 + c] = bits;
    }
}

// ---------------------------------------------------------------------------
// Transpose + convert: x NCHW fp32 -> xt [pixel][channel] bf16.
// Tile: 32 hw x 128 c. Reads: float4 (128 B/row). Writes: uint4/lane,
// 256 B contiguous per pixel row. LDS [32][132] fp32: 2-way max aliasing.
// ---------------------------------------------------------------------------
__global__ __launch_bounds__(256) void transpose_kernel(
        const float* __restrict__ x, ushort_t* __restrict__ xt) {
    __shared__ float L[32][132];
    const int hw0 = blockIdx.x * 32;
    const int c0  = blockIdx.y * 128;
    const int n   = blockIdx.z;
    const int t = threadIdx.x;
    const int c_ = t >> 1;        // 0..127
    const int half = t & 1;

    const float* src = x + (size_t)(n * CIN + c0 + c_) * IMG + hw0 + half * 16;
    float4 v[4];
#pragma unroll
    for (int k = 0; k < 4; ++k) v[k] = *(const float4*)(src + k * 4);
#pragma unroll
    for (int k = 0; k < 4; ++k) {
        L[half * 16 + k * 4 + 0][c_] = v[k].x;
        L[half * 16 + k * 4 + 1][c_] = v[k].y;
        L[half * 16 + k * 4 + 2][c_] = v[k].z;
        L[half * 16 + k * 4 + 3][c_] = v[k].w;
    }
    __syncthreads();

    const int seg = t & 15;       // 8-channel segment
    const int hwb = t >> 4;       // 0..15
#pragma unroll
    for (int j = 0; j < 2; ++j) {
        const int hwl = hwb + j * 16;
        const float* row = &L[hwl][seg * 8];
        uint_t pk[4];
#pragma unroll
        for (int q = 0; q < 4; ++q)
            pk[q] = (uint_t)f2bf(row[2 * q]) | ((uint_t)f2bf(row[2 * q + 1]) << 16);
        *(uint4*)&xt[(size_t)(n * IMG + hw0 + hwl) * CIN + c0 + seg * 8] =
            (uint4){pk[0], pk[1], pk[2], pk[3]};
    }
}

// ---------------------------------------------------------------------------
// Implicit-GEMM conv: 128x128 tile, BK=64 (two 32-ch MFMA chunks per barrier
// pair -> half the barrier drains of BK=32). Loop c0-outer/kpos-inner for L2
// reuse of the 9-tap neighborhood. XOR-8 swizzle: LDS seg s of row r holds
// global seg s^(r&7); staging lane l covers row ..+（l>>3), seg l&7 -> source
// seg (l&7)^((l>>3)&7). Halo pixels redirect to zeroed pad row NPIX.
// ---------------------------------------------------------------------------
__global__ __launch_bounds__(256) void tern_conv_kernel(
        const ushort_t* __restrict__ xt,    // [(NPIX+1)][256]
        const ushort_t* __restrict__ wt2,   // [256 o][9][256 c]
        const float* __restrict__ alpha,
        const float* __restrict__ bias,
        float* __restrict__ out) {
    __shared__ __align__(16) ushort_t As[BM * BK];   // 16 KB
    __shared__ __align__(16) ushort_t Xs[BN * BK];   // 16 KB

    const int tid = threadIdx.x;
    const int wv = tid >> 6;
    const int l = tid & 63;
    const int bid = blockIdx.x;
    const int o0 = (bid & 1) * BM;
    const int p0 = (bid >> 1) * BN;

    const int subrow = l >> 3;          // 0..7
    const int g = (l & 7) ^ subrow;     // swizzled global 8-ch segment

    // per-lane A sources and B pixel decodes (4 rows each, stride 8)
    const ushort_t* aptr[4];
    int ximg[4], xh[4], xw[4];
#pragma unroll
    for (int i = 0; i < 4; ++i) {
        int r = wv * 32 + i * 8 + subrow;
        aptr[i] = wt2 + (size_t)(o0 + r) * K_TOT + g * 8;
        int p = p0 + r;
        int n_img = p / IMG;
        int hw_ = p - n_img * IMG;
        xh[i] = hw_ / HWDIM;
        xw[i] = hw_ - xh[i] * HWDIM;
        ximg[i] = n_img * IMG;
    }

    // wave-uniform LDS staging destinations
    ushort_t* adst[4]; ushort_t* xdst[4];
#pragma unroll
    for (int i = 0; i < 4; ++i) {
        adst[i] = &As[(wv * 32 + i * 8) * BK];
        xdst[i] = &Xs[(wv * 32 + i * 8) * BK];
    }

    // fragment-read geometry
    const int qd = l >> 4, ln = l & 15;
    const int wm = (wv >> 1) * 64, wn = (wv & 1) * 64;
    const int sbase = (qd ^ (ln & 7)) * 8;   // de-swizzle, chunk h adds ^32
    int arow[4], xrow[4];
#pragma unroll
    for (int i = 0; i < 4; ++i) {
        arow[i] = (wm + i * 16 + ln) * BK;
        xrow[i] = (wn + i * 16 + ln) * BK;
    }

    f32x4 acc[4][4];
#pragma unroll
    for (int i = 0; i < 4; ++i)
#pragma unroll
        for (int j = 0; j < 4; ++j)
            acc[i][j] = (f32x4){0.f, 0.f, 0.f, 0.f};

#pragma unroll 1
    for (int c0 = 0; c0 < CIN; c0 += BK) {
#pragma unroll 1
        for (int kpos = 0; kpos < 9; ++kpos) {
            const int dh = kpos / 3 - 1;
            const int dw = kpos - (dh + 1) * 3 - 1;
            const ushort_t* xsrc[4];
#pragma unroll
            for (int i = 0; i < 4; ++i) {
                int h2 = xh[i] + dh, w2 = xw[i] + dw;
                int row = ((unsigned)h2 < (unsigned)HWDIM && (unsigned)w2 < (unsigned)HWDIM)
                              ? (ximg[i] + h2 * HWDIM + w2) : NPIX;
                xsrc[i] = xt + (size_t)row * CIN + g * 8 + c0;
            }
            const int aoff = kpos * 256 + c0;

            __syncthreads();   // previous step's fragment reads complete
#pragma unroll
            for (int i = 0; i < 4; ++i)
                __builtin_amdgcn_global_load_lds(AS1CAST(aptr[i] + aoff), AS3CAST(adst[i]), 16, 0, 0);
#pragma unroll
            for (int i = 0; i < 4; ++i)
                __builtin_amdgcn_global_load_lds(AS1CAST(xsrc[i]), AS3CAST(xdst[i]), 16, 0, 0);
            __syncthreads();   // staging landed

#pragma unroll
            for (int h = 0; h < 2; ++h) {
                const int so = sbase ^ (h * 32);
                bf16x8 af[4], bfr[4];
#pragma unroll
                for (int i = 0; i < 4; ++i)
                    af[i] = *(const bf16x8*)&As[arow[i] + so];
#pragma unroll
                for (int i = 0; i < 4; ++i)
                    bfr[i] = *(const bf16x8*)&Xs[xrow[i] + so];
#pragma unroll
                for (int im = 0; im < 4; ++im)
#pragma unroll
                    for (int in2 = 0; in2 < 4; ++in2)
                        acc[im][in2] = __builtin_amdgcn_mfma_f32_16x16x32_bf16(
                            af[im], bfr[in2], acc[im][in2], 0, 0, 0);
            }
        }
    }

    // epilogue: out[n][o][h][w] = alpha[o]*acc + bias[o]
#pragma unroll
    for (int im = 0; im < 4; ++im) {
        const int orow = o0 + wm + im * 16 + qd * 4;
        const f32x4 al = *(const f32x4*)&alpha[orow];
        const f32x4 bi = *(const f32x4*)&bias[orow];
#pragma unroll
        for (int in2 = 0; in2 < 4; ++in2) {
            const int pc = p0 + wn + in2 * 16 + ln;
            const int ni = pc / IMG;
            const int hwc = pc - ni * IMG;
            const size_t obase = (size_t)ni * COUT * IMG + hwc;
#pragma unroll
            for (int rr = 0; rr < 4; ++rr)
                out[obase + (size_t)(orow + rr) * IMG] = al[rr] * acc[im][in2][rr] + bi[rr];
        }
    }
}

extern "C" void kernel_launch(void* const* d_in, const int* in_sizes, int n_in,
                              void* d_out, int out_size, void* d_ws, size_t ws_size,
                              hipStream_t stream) {
    const float* x      = (const float*)d_in[0];
    const float* weight = (const float*)d_in[1];
    const float* bias   = (const float*)d_in[2];
    float* out = (float*)d_out;

    // workspace: xt (NPIX+1)*256 bf16 (last row = zero halo), wt2, alpha
    ushort_t* xt     = (ushort_t*)d_ws;
    ushort_t* wt2    = (ushort_t*)((char*)d_ws + (size_t)(NPIX + 1) * CIN * sizeof(ushort_t));
    float*    alphav = (float*)((char*)wt2 + (size_t)COUT * K_TOT * sizeof(ushort_t));

    ternarize_kernel<<<COUT, 256, 0, stream>>>(weight, wt2, alphav,
                                               xt + (size_t)NPIX * CIN);

    dim3 tg(IMG / 32, CIN / 128, NIMG);  // 98 x 2 x 32
    transpose_kernel<<<tg, 256, 0, stream>>>(x, xt);

    const int n_blocks = (COUT / BM) * (NPIX / BN);  // 1568
    tern_conv_kernel<<<n_blocks, 256, 0, stream>>>(xt, wt2, alphav, bias, out);
}